// Round 5
// baseline (1862.431 us; speedup 1.0000x reference)
//
#include <hip/hip_runtime.h>
#include <hip/hip_fp16.h>
#include <math.h>

// ---------------------------------------------------------------------------
// CGNR solver: v = argmin ||H v - x|| via CG on (H^T H) v = H^T x, 32 iters,
// then reconstruction + time/frequency metrics.  N = 8192.
//
// Round 10: widen the spart reduction.  Round-9 post-mortem: fused_pass is
// near its BW roofline (~26 us); the hidden cost was reduce_update running
// on only 32 blocks (32/256 CUs -> ~0.8 TB/s share for a 16 MB stream ->
// ~15-20 us x33).  New reduce_update: 512 blocks x 512 thr, 16 columns per
// block, 32 partial-groups of nb/32 partials each, LDS-combined; all CUs
// active -> ~4-5 us.  fused_pass unchanged from round 9 (register-resident
// H, lgkmcnt-only per-step barrier).
//
// sc[] slots: RS[it]=sc[it] (0..32), TT[it]=sc[40+it], metrics msc=sc+80.
// ---------------------------------------------------------------------------

#define NN 8192
#define NITER 32
#define EPSF 1e-20f

typedef unsigned short ushort_t;

__device__ __forceinline__ float wave_red(float v) {
    #pragma unroll
    for (int off = 32; off; off >>= 1) v += __shfl_xor(v, off, 64);
    return v;
}

__device__ __forceinline__ void wred_atomic(float v, float* addr) {
    v = wave_red(v);
    if ((threadIdx.x & 63) == 0) atomicAdd(addr, v);
}

__device__ __forceinline__ void unpack8(uint4 u, float* f) {
    union { unsigned int i; __half2 h; } c0, c1, c2, c3;
    c0.i = u.x; c1.i = u.y; c2.i = u.z; c3.i = u.w;
    float2 f0 = __half22float2(c0.h);
    float2 f1 = __half22float2(c1.h);
    float2 f2 = __half22float2(c2.h);
    float2 f3 = __half22float2(c3.h);
    f[0] = f0.x; f[1] = f0.y; f[2] = f1.x; f[3] = f1.y;
    f[4] = f2.x; f[5] = f2.y; f[6] = f3.x; f[7] = f3.y;
}

// --- packed row fragment (one thread's 16 columns of one H row) ------------
template <int HM> struct RowT;
template <> struct RowT<1> { uint4 a, b; };          // 16 fp16
template <> struct RowT<0> { float f[16]; };         // 16 fp32

__device__ __forceinline__ void load_row(const void* Hp, int row, int tid,
                                         RowT<1>& c) {
    const uint4* hp = (const uint4*)((const ushort_t*)Hp + (size_t)row * NN)
                    + tid * 2;
    c.a = hp[0]; c.b = hp[1];
}
__device__ __forceinline__ void load_row(const void* Hp, int row, int tid,
                                         RowT<0>& c) {
    const float4* hp = (const float4*)((const float*)Hp + (size_t)row * NN)
                     + tid * 4;
    #pragma unroll
    for (int q = 0; q < 4; ++q) {
        float4 v = hp[q];
        c.f[4*q+0] = v.x; c.f[4*q+1] = v.y; c.f[4*q+2] = v.z; c.f[4*q+3] = v.w;
    }
}
__device__ __forceinline__ void unpack_row(const RowT<1>& c, float* f) {
    unpack8(c.a, f); unpack8(c.b, f + 8);
}
__device__ __forceinline__ void unpack_row(const RowT<0>& c, float* f) {
    #pragma unroll
    for (int k = 0; k < 16; ++k) f[k] = c.f[k];
}

// --- fused normal-equations pass -------------------------------------------
// mode 1:  pn = r + beta*p ; t = H pn ; TT += ||t||^2 ;
//          spart[blk] = sum_{rows of blk} t_i * H[i,:] ; block0 stores pn.
//          H rows stay in REGISTERS between the dot and the axpy; the
//          per-step barrier waits lgkmcnt ONLY (prefetch stays in flight).
// mode 0:  spart[blk] = sum_{rows of blk} x_i * H[i,:]   (b = H^T x init);
//          CONV=1 additionally writes the fp16 copy of H.
// grid nb x 512 thr; thread owns 16 columns; rpb = NN/nb rows/block (even).
template <int HM, int CONV>
__global__ __launch_bounds__(512, 4) void fused_pass(
        const void* __restrict__ Hp,
        ushort_t* __restrict__ Hh_out,
        const float* __restrict__ rr,
        const float* __restrict__ pp,
        const float* __restrict__ x,
        const float* __restrict__ sc,
        int bnum, int bden, int first, int mode, int rpb,
        float* __restrict__ tout,
        float* __restrict__ ttout,
        float* __restrict__ pout,
        float* __restrict__ spart) {
    const int tid  = threadIdx.x;
    const int wave = tid >> 6;
    const int lane = tid & 63;
    __shared__ __align__(16) float prt[2][16];   // [buf][2*wave+{0,1}]

    float sacc[16];
    #pragma unroll
    for (int k = 0; k < 16; ++k) sacc[k] = 0.f;

    const int rbase = blockIdx.x * rpb;

    if (mode == 0) {
        // ---- init: b = H^T x (single sweep; optional fp32->fp16 convert) --
        #pragma unroll 2
        for (int i = 0; i < rpb; ++i) {
            const int row = rbase + i;
            RowT<HM> c;
            load_row(Hp, row, tid, c);
            float f[16];
            unpack_row(c, f);
            if (CONV) {
                uint4 pa, pb;
                __half2 h0 = __floats2half2_rn(f[0],  f[1]);
                __half2 h1 = __floats2half2_rn(f[2],  f[3]);
                __half2 h2 = __floats2half2_rn(f[4],  f[5]);
                __half2 h3 = __floats2half2_rn(f[6],  f[7]);
                __half2 h4 = __floats2half2_rn(f[8],  f[9]);
                __half2 h5 = __floats2half2_rn(f[10], f[11]);
                __half2 h6 = __floats2half2_rn(f[12], f[13]);
                __half2 h7 = __floats2half2_rn(f[14], f[15]);
                pa.x = *(unsigned int*)&h0; pa.y = *(unsigned int*)&h1;
                pa.z = *(unsigned int*)&h2; pa.w = *(unsigned int*)&h3;
                pb.x = *(unsigned int*)&h4; pb.y = *(unsigned int*)&h5;
                pb.z = *(unsigned int*)&h6; pb.w = *(unsigned int*)&h7;
                uint4* dst = (uint4*)(Hh_out + (size_t)row * NN) + tid * 2;
                dst[0] = pa; dst[1] = pb;
            }
            const float xv = x[row];
            #pragma unroll
            for (int k = 0; k < 16; ++k) sacc[k] += xv * f[k];
        }
    } else {
        // ---- CG iteration: pn build, then 2-rows-per-step pipeline --------
        float pn[16];
        const float beta = first ? 0.f : sc[bnum] / (sc[bden] + EPSF);
        {
            const float4* r4 = (const float4*)rr + tid * 4;
            const float4* p4 = (const float4*)pp + tid * 4;
            #pragma unroll
            for (int q = 0; q < 4; ++q) {
                float4 a = r4[q], b = p4[q];
                pn[4*q+0] = a.x + beta * b.x; pn[4*q+1] = a.y + beta * b.y;
                pn[4*q+2] = a.z + beta * b.z; pn[4*q+3] = a.w + beta * b.w;
            }
            if (blockIdx.x == 0) {
                float4* o4 = (float4*)pout + tid * 4;
                #pragma unroll
                for (int q = 0; q < 4; ++q) {
                    float4 w;
                    w.x = pn[4*q+0]; w.y = pn[4*q+1];
                    w.z = pn[4*q+2]; w.w = pn[4*q+3];
                    o4[q] = w;
                }
            }
        }

        const int nstep = rpb >> 1;          // 2 rows per step
        float ttacc = 0.f;
        RowT<HM> c0, c1, n0, n1;
        load_row(Hp, rbase + 0, tid, c0);
        load_row(Hp, rbase + 1, tid, c1);

        for (int k = 0; k < nstep; ++k) {
            if (k + 1 < nstep) {              // prefetch next pair (stays in
                load_row(Hp, rbase + 2 * (k + 1) + 0, tid, n0);   // flight
                load_row(Hp, rbase + 2 * (k + 1) + 1, tid, n1);   // across
            }                                                     // barrier)
            float f0[16], f1[16];
            unpack_row(c0, f0);
            unpack_row(c1, f1);
            float dA = 0.f, dB = 0.f;
            #pragma unroll
            for (int j = 0; j < 16; ++j) { dA += f0[j] * pn[j]; dB += f1[j] * pn[j]; }
            dA = wave_red(dA); dB = wave_red(dB);
            const int kb = k & 1;
            if (lane == 0) { prt[kb][2 * wave] = dA; prt[kb][2 * wave + 1] = dB; }
            // commit the LDS write, then raw barrier: lgkmcnt ONLY — the
            // global prefetch loads are NOT drained here (measured-neutral
            // vs __syncthreads, kept as the cheaper ordering).
            asm volatile("s_waitcnt lgkmcnt(0)" ::: "memory");
            __builtin_amdgcn_s_barrier();
            const float4* pq = (const float4*)prt[kb];
            float4 q0 = pq[0], q1 = pq[1], q2 = pq[2], q3 = pq[3];
            const float tvA = q0.x + q0.z + q1.x + q1.z
                            + q2.x + q2.z + q3.x + q3.z;
            const float tvB = q0.y + q0.w + q1.y + q1.w
                            + q2.y + q2.w + q3.y + q3.w;
            if (tid == 0) {
                tout[rbase + 2 * k + 0] = tvA;
                tout[rbase + 2 * k + 1] = tvB;
                ttacc += tvA * tvA + tvB * tvB;
            }
            #pragma unroll
            for (int j = 0; j < 16; ++j) sacc[j] += tvA * f0[j] + tvB * f1[j];
            c0 = n0; c1 = n1;                 // register renames
        }
        if (tid == 0) atomicAdd(ttout, ttacc);
    }

    float4* sp = (float4*)(spart + (size_t)blockIdx.x * NN) + tid * 4;
    #pragma unroll
    for (int q = 0; q < 4; ++q) {
        float4 w;
        w.x = sacc[4*q+0]; w.y = sacc[4*q+1];
        w.z = sacc[4*q+2]; w.w = sacc[4*q+3];
        sp[q] = w;
    }
}

// --- combine spart column-wise -> s ; apply CG update ----------------------
// 512 blocks x 512 thr; block owns 16 columns (all 256 CUs active).
// Thread (pg, colq): sums nb/32 partials for col = blk*16+colq; LDS combine.
// mode 0: r = s, RS += s^2
// mode 1: alpha=RS/TT; v += alpha pn; qh += alpha t; r -= alpha s; RS' += r^2
__global__ __launch_bounds__(512) void reduce_update(
        const float* __restrict__ spart, int nb,
        const float* __restrict__ t,
        const float* __restrict__ pn,
        float* __restrict__ r,
        float* __restrict__ v,
        float* __restrict__ qh,
        const float* __restrict__ sc,
        int anum, int aden,
        float* __restrict__ rsout,
        int mode) {
    const int tid  = threadIdx.x;
    const int colq = tid & 15;            // 0..15: column within block
    const int pg   = tid >> 4;            // 0..31: partial-group
    const int col  = blockIdx.x * 16 + colq;
    const int per  = nb >> 5;             // partials per group (nb=512 -> 16)
    float s = 0.f;
    #pragma unroll 16
    for (int i = 0; i < per; ++i)
        s += spart[(size_t)(pg * per + i) * NN + col];
    __shared__ float sred[32][17];
    sred[pg][colq] = s;
    __syncthreads();
    float rn2 = 0.f;
    if (tid < 16) {
        float ssum = 0.f;
        #pragma unroll
        for (int g = 0; g < 32; ++g) ssum += sred[g][tid];
        const int c = blockIdx.x * 16 + tid;
        float rn;
        if (mode == 0) {
            rn = ssum;
        } else {
            const float alpha = sc[anum] / (sc[aden] + EPSF);
            v[c]  += alpha * pn[c];
            qh[c] += alpha * t[c];
            rn = r[c] - alpha * ssum;
        }
        r[c] = rn;
        rn2 = rn * rn;
    }
    if (tid < 64) {
        rn2 = wave_red(rn2);
        if (tid == 0) atomicAdd(rsout, rn2);
    }
}

// --- prep: zero v, qh and scalar slots ------------------------------------
__global__ __launch_bounds__(256) void prep(float* v, float* qh, float* sc) {
    const int i = blockIdx.x * 256 + threadIdx.x;
    v[i] = 0.f; qh[i] = 0.f;
    if (i < 128) sc[i] = 0.f;
}

// --- time-domain metrics + difference signals + v output ------------------
__global__ __launch_bounds__(256) void metrics1(const float* __restrict__ qh,
                                                const float* __restrict__ v,
                                                const float* __restrict__ x,
                                                const float* __restrict__ vt,
                                                const float* __restrict__ qt,
                                                float* __restrict__ dv,
                                                float* __restrict__ dq,
                                                float* msc,
                                                float* __restrict__ out) {
    const int i = blockIdx.x * 256 + threadIdx.x;
    const float qhv = qh[i], vv = v[i];
    const float xv = x[i], vtv = vt[i], qtv = qt[i];
    const float dqi = qhv - qtv, dvi = vv - vtv;
    dq[i] = dqi; dv[i] = dvi;
    out[i] = vv;
    const float sg = (i & 1) ? -1.f : 1.f;
    const float rx = qhv - xv;
    wred_atomic(rx * rx,    &msc[3]);
    wred_atomic(fabsf(dqi), &msc[4]);
    wred_atomic(dqi * dqi,  &msc[5]);
    wred_atomic(qtv * qtv,  &msc[6]);
    wred_atomic(fabsf(dvi), &msc[7]);
    wred_atomic(dvi * dvi,  &msc[8]);
    wred_atomic(vtv * vtv,  &msc[9]);
    wred_atomic(dqi,        &msc[10]);
    wred_atomic(sg * dqi,   &msc[11]);
    wred_atomic(qtv,        &msc[12]);
    wred_atomic(sg * qtv,   &msc[13]);
    wred_atomic(dvi,        &msc[14]);
    wred_atomic(sg * dvi,   &msc[15]);
    wred_atomic(vtv,        &msc[16]);
    wred_atomic(sg * vtv,   &msc[17]);
}

// --- direct rDFT magnitudes: one wave per bin k (0..4096) ------------------
__global__ __launch_bounds__(256) void dftmag(const float* __restrict__ dv,
                                              const float* __restrict__ dq,
                                              float* msc) {
    const int wave = threadIdx.x >> 6;
    const int lane = threadIdx.x & 63;
    const int k = blockIdx.x * 4 + wave;
    const float* sig = blockIdx.y ? dq : dv;
    float re = 0.f, im = 0.f;
    if (k <= 4096) {
        const float C = 2.0f * 3.14159265358979323846f / 8192.0f;
        int phase = (k * lane) & 8191;
        const int step = (k << 6) & 8191;
        for (int j = 0; j < 128; ++j) {
            const float s = sig[j * 64 + lane];
            float sn, cs;
            sincosf(C * (float)phase, &sn, &cs);
            re += s * cs; im += s * sn;
            phase = (phase + step) & 8191;
        }
    }
    re = wave_red(re); im = wave_red(im);
    __shared__ float mg[4];
    if (lane == 0) mg[wave] = (k <= 4096) ? sqrtf(re * re + im * im) : 0.f;
    __syncthreads();
    if (threadIdx.x == 0)
        atomicAdd(&msc[18 + blockIdx.y], mg[0] + mg[1] + mg[2] + mg[3]);
}

// --- finalize 11 scalar outputs -------------------------------------------
__global__ void finalize(const float* __restrict__ msc,
                         float* __restrict__ out) {
    if (threadIdx.x == 0 && blockIdx.x == 0) {
        const float Nf = 8192.0f;
        const float Sdq = 0.5f * (Nf * msc[5] + msc[10]*msc[10] + msc[11]*msc[11]);
        const float Sqt = 0.5f * (Nf * msc[6] + msc[12]*msc[12] + msc[13]*msc[13]);
        const float Sdv = 0.5f * (Nf * msc[8] + msc[14]*msc[14] + msc[15]*msc[15]);
        const float Svt = 0.5f * (Nf * msc[9] + msc[16]*msc[16] + msc[17]*msc[17]);
        out[8192 + 0]  = sqrtf(msc[3]);
        out[8192 + 1]  = msc[4] / Nf;
        out[8192 + 2]  = msc[5] / (msc[6] + EPSF);
        out[8192 + 3]  = msc[7] / Nf;
        out[8192 + 4]  = msc[8] / (msc[9] + EPSF);
        out[8192 + 5]  = msc[5] / Nf;
        out[8192 + 6]  = msc[8] / Nf;
        out[8192 + 7]  = msc[19] / 4097.0f;
        out[8192 + 8]  = Sdq / (Sqt + EPSF);
        out[8192 + 9]  = msc[18] / 4097.0f;
        out[8192 + 10] = Sdv / (Svt + EPSF);
    }
}

// ---------------------------------------------------------------------------
extern "C" void kernel_launch(void* const* d_in, const int* in_sizes, int n_in,
                              void* d_out, int out_size, void* d_ws, size_t ws_size,
                              hipStream_t stream) {
    const float* x  = (const float*)d_in[1];
    const float* H  = (const float*)d_in[2];
    const float* vt = (const float*)d_in[3];
    const float* qt = (const float*)d_in[4];

    const size_t HH_BYTES  = (size_t)NN * NN * 2;   // 134,217,728 (fp16 H)
    const size_t VEC_BYTES = 80000ull * 4;

    int nb = 512;                                    // row-blocks in fused pass
    const bool fp16ok =
        ws_size >= HH_BYTES + (size_t)512 * NN * 4 + VEC_BYTES;

    ushort_t* Hh = (ushort_t*)d_ws;
    float* spart;
    float* vecs;
    if (fp16ok) {
        spart = (float*)((char*)d_ws + HH_BYTES);
        vecs  = spart + (size_t)512 * NN;
    } else {
        // fp32-direct fallback: only spart + vectors in ws
        while (nb > 64 && ws_size < (size_t)nb * NN * 4 + VEC_BYTES) nb >>= 1;
        spart = (float*)d_ws;
        vecs  = spart + (size_t)nb * NN;
    }
    const int rpb = NN / nb;

    float* v   = vecs;
    float* r   = vecs + 8192;
    float* pA  = vecs + 16384;
    float* pB  = vecs + 24576;
    float* t   = vecs + 32768;
    float* qh  = vecs + 40960;
    float* dv  = vecs + 49152;
    float* dq  = vecs + 57344;
    float* sc  = vecs + 65536;
    float* msc = sc + 80;
    float* out = (float*)d_out;
    float* pbuf[2] = { pA, pB };

    prep<<<32, 256, 0, stream>>>(v, qh, sc);

    // init: b = H^T x  ->  r = b, RS[0] = b.b   (+ fp16 convert when fp16ok)
    if (fp16ok)
        fused_pass<0, 1><<<nb, 512, 0, stream>>>(H, Hh, r, r, x, sc,
                                                 0, 0, 1, 0, rpb,
                                                 t, &sc[79], pA, spart);
    else
        fused_pass<0, 0><<<nb, 512, 0, stream>>>(H, nullptr, r, r, x, sc,
                                                 0, 0, 1, 0, rpb,
                                                 t, &sc[79], pA, spart);
    reduce_update<<<512, 512, 0, stream>>>(spart, nb, t, pA, r, v, qh, sc,
                                           0, 0, &sc[0], 0);

    for (int it = 0; it < NITER; ++it) {
        const float* pread = (it == 0) ? r : pbuf[(it - 1) & 1];
        float* pwrite = pbuf[it & 1];
        if (fp16ok)
            fused_pass<1, 0><<<nb, 512, 0, stream>>>(Hh, nullptr, r, pread, x,
                                                     sc, it, it - 1,
                                                     (it == 0) ? 1 : 0, 1, rpb,
                                                     t, &sc[40 + it],
                                                     pwrite, spart);
        else
            fused_pass<0, 0><<<nb, 512, 0, stream>>>(H, nullptr, r, pread, x,
                                                     sc, it, it - 1,
                                                     (it == 0) ? 1 : 0, 1, rpb,
                                                     t, &sc[40 + it],
                                                     pwrite, spart);
        reduce_update<<<512, 512, 0, stream>>>(spart, nb, t, pwrite, r, v, qh,
                                               sc, it, 40 + it, &sc[it + 1], 1);
    }

    metrics1<<<32, 256, 0, stream>>>(qh, v, x, vt, qt, dv, dq, msc, out);
    dim3 g(1025, 2);
    dftmag<<<g, 256, 0, stream>>>(dv, dq, msc);
    finalize<<<1, 64, 0, stream>>>(sc + 80, out);
}

// Round 7
// 1653.600 us; speedup vs baseline: 1.1263x; 1.1263x over previous
//
#include <hip/hip_runtime.h>
#include <hip/hip_fp16.h>
#include <math.h>

// ---------------------------------------------------------------------------
// CGNR solver: v = argmin ||H v - x|| via CG on (H^T H) v = H^T x, 32 iters,
// then reconstruction + time/frequency metrics.  N = 8192.
//
// Round 11 (resubmit; round-6 bench was an infra failure): line-aligned wide
// reduction.  Round-10's 512-block reduce gave each block 16 cols = 64 B ->
// every 128 B line split across two blocks on different CUs -> 2x read
// traffic (regressed).  Round-9's 32-block version was coalesced but used
// 32/256 CUs (0.79 TB/s share -> ~20 us).  Fix: 256 blocks x 512 thr, each
// block owns 32 CONSECUTIVE cols = one full 128 B line; all CUs active,
// zero line waste -> ~5 us.  fused_pass unchanged (register-resident H,
// one H read per iteration).
//
// sc[] slots: RS[it]=sc[it] (0..32), TT[it]=sc[40+it], metrics msc=sc+80.
// ---------------------------------------------------------------------------

#define NN 8192
#define NITER 32
#define EPSF 1e-20f

typedef unsigned short ushort_t;

__device__ __forceinline__ float wave_red(float v) {
    #pragma unroll
    for (int off = 32; off; off >>= 1) v += __shfl_xor(v, off, 64);
    return v;
}

__device__ __forceinline__ void wred_atomic(float v, float* addr) {
    v = wave_red(v);
    if ((threadIdx.x & 63) == 0) atomicAdd(addr, v);
}

__device__ __forceinline__ void unpack8(uint4 u, float* f) {
    union { unsigned int i; __half2 h; } c0, c1, c2, c3;
    c0.i = u.x; c1.i = u.y; c2.i = u.z; c3.i = u.w;
    float2 f0 = __half22float2(c0.h);
    float2 f1 = __half22float2(c1.h);
    float2 f2 = __half22float2(c2.h);
    float2 f3 = __half22float2(c3.h);
    f[0] = f0.x; f[1] = f0.y; f[2] = f1.x; f[3] = f1.y;
    f[4] = f2.x; f[5] = f2.y; f[6] = f3.x; f[7] = f3.y;
}

// --- packed row fragment (one thread's 16 columns of one H row) ------------
template <int HM> struct RowT;
template <> struct RowT<1> { uint4 a, b; };          // 16 fp16
template <> struct RowT<0> { float f[16]; };         // 16 fp32

__device__ __forceinline__ void load_row(const void* Hp, int row, int tid,
                                         RowT<1>& c) {
    const uint4* hp = (const uint4*)((const ushort_t*)Hp + (size_t)row * NN)
                    + tid * 2;
    c.a = hp[0]; c.b = hp[1];
}
__device__ __forceinline__ void load_row(const void* Hp, int row, int tid,
                                         RowT<0>& c) {
    const float4* hp = (const float4*)((const float*)Hp + (size_t)row * NN)
                     + tid * 4;
    #pragma unroll
    for (int q = 0; q < 4; ++q) {
        float4 v = hp[q];
        c.f[4*q+0] = v.x; c.f[4*q+1] = v.y; c.f[4*q+2] = v.z; c.f[4*q+3] = v.w;
    }
}
__device__ __forceinline__ void unpack_row(const RowT<1>& c, float* f) {
    unpack8(c.a, f); unpack8(c.b, f + 8);
}
__device__ __forceinline__ void unpack_row(const RowT<0>& c, float* f) {
    #pragma unroll
    for (int k = 0; k < 16; ++k) f[k] = c.f[k];
}

// --- fused normal-equations pass -------------------------------------------
// mode 1:  pn = r + beta*p ; t = H pn ; TT += ||t||^2 ;
//          spart[blk] = sum_{rows of blk} t_i * H[i,:] ; block0 stores pn.
//          H rows stay in REGISTERS between the dot and the axpy; the
//          per-step barrier waits lgkmcnt ONLY (prefetch stays in flight).
// mode 0:  spart[blk] = sum_{rows of blk} x_i * H[i,:]   (b = H^T x init);
//          CONV=1 additionally writes the fp16 copy of H.
// grid nb x 512 thr; thread owns 16 columns; rpb = NN/nb rows/block (even).
template <int HM, int CONV>
__global__ __launch_bounds__(512, 4) void fused_pass(
        const void* __restrict__ Hp,
        ushort_t* __restrict__ Hh_out,
        const float* __restrict__ rr,
        const float* __restrict__ pp,
        const float* __restrict__ x,
        const float* __restrict__ sc,
        int bnum, int bden, int first, int mode, int rpb,
        float* __restrict__ tout,
        float* __restrict__ ttout,
        float* __restrict__ pout,
        float* __restrict__ spart) {
    const int tid  = threadIdx.x;
    const int wave = tid >> 6;
    const int lane = tid & 63;
    __shared__ __align__(16) float prt[2][16];   // [buf][2*wave+{0,1}]

    float sacc[16];
    #pragma unroll
    for (int k = 0; k < 16; ++k) sacc[k] = 0.f;

    const int rbase = blockIdx.x * rpb;

    if (mode == 0) {
        // ---- init: b = H^T x (single sweep; optional fp32->fp16 convert) --
        #pragma unroll 2
        for (int i = 0; i < rpb; ++i) {
            const int row = rbase + i;
            RowT<HM> c;
            load_row(Hp, row, tid, c);
            float f[16];
            unpack_row(c, f);
            if (CONV) {
                uint4 pa, pb;
                __half2 h0 = __floats2half2_rn(f[0],  f[1]);
                __half2 h1 = __floats2half2_rn(f[2],  f[3]);
                __half2 h2 = __floats2half2_rn(f[4],  f[5]);
                __half2 h3 = __floats2half2_rn(f[6],  f[7]);
                __half2 h4 = __floats2half2_rn(f[8],  f[9]);
                __half2 h5 = __floats2half2_rn(f[10], f[11]);
                __half2 h6 = __floats2half2_rn(f[12], f[13]);
                __half2 h7 = __floats2half2_rn(f[14], f[15]);
                pa.x = *(unsigned int*)&h0; pa.y = *(unsigned int*)&h1;
                pa.z = *(unsigned int*)&h2; pa.w = *(unsigned int*)&h3;
                pb.x = *(unsigned int*)&h4; pb.y = *(unsigned int*)&h5;
                pb.z = *(unsigned int*)&h6; pb.w = *(unsigned int*)&h7;
                uint4* dst = (uint4*)(Hh_out + (size_t)row * NN) + tid * 2;
                dst[0] = pa; dst[1] = pb;
            }
            const float xv = x[row];
            #pragma unroll
            for (int k = 0; k < 16; ++k) sacc[k] += xv * f[k];
        }
    } else {
        // ---- CG iteration: pn build, then 2-rows-per-step pipeline --------
        float pn[16];
        const float beta = first ? 0.f : sc[bnum] / (sc[bden] + EPSF);
        {
            const float4* r4 = (const float4*)rr + tid * 4;
            const float4* p4 = (const float4*)pp + tid * 4;
            #pragma unroll
            for (int q = 0; q < 4; ++q) {
                float4 a = r4[q], b = p4[q];
                pn[4*q+0] = a.x + beta * b.x; pn[4*q+1] = a.y + beta * b.y;
                pn[4*q+2] = a.z + beta * b.z; pn[4*q+3] = a.w + beta * b.w;
            }
            if (blockIdx.x == 0) {
                float4* o4 = (float4*)pout + tid * 4;
                #pragma unroll
                for (int q = 0; q < 4; ++q) {
                    float4 w;
                    w.x = pn[4*q+0]; w.y = pn[4*q+1];
                    w.z = pn[4*q+2]; w.w = pn[4*q+3];
                    o4[q] = w;
                }
            }
        }

        const int nstep = rpb >> 1;          // 2 rows per step
        float ttacc = 0.f;
        RowT<HM> c0, c1, n0, n1;
        load_row(Hp, rbase + 0, tid, c0);
        load_row(Hp, rbase + 1, tid, c1);

        for (int k = 0; k < nstep; ++k) {
            if (k + 1 < nstep) {              // prefetch next pair (stays in
                load_row(Hp, rbase + 2 * (k + 1) + 0, tid, n0);   // flight
                load_row(Hp, rbase + 2 * (k + 1) + 1, tid, n1);   // across
            }                                                     // barrier)
            float f0[16], f1[16];
            unpack_row(c0, f0);
            unpack_row(c1, f1);
            float dA = 0.f, dB = 0.f;
            #pragma unroll
            for (int j = 0; j < 16; ++j) { dA += f0[j] * pn[j]; dB += f1[j] * pn[j]; }
            dA = wave_red(dA); dB = wave_red(dB);
            const int kb = k & 1;
            if (lane == 0) { prt[kb][2 * wave] = dA; prt[kb][2 * wave + 1] = dB; }
            // commit the LDS write, then raw barrier: lgkmcnt ONLY — the
            // global prefetch loads are NOT drained here.
            asm volatile("s_waitcnt lgkmcnt(0)" ::: "memory");
            __builtin_amdgcn_s_barrier();
            const float4* pq = (const float4*)prt[kb];
            float4 q0 = pq[0], q1 = pq[1], q2 = pq[2], q3 = pq[3];
            const float tvA = q0.x + q0.z + q1.x + q1.z
                            + q2.x + q2.z + q3.x + q3.z;
            const float tvB = q0.y + q0.w + q1.y + q1.w
                            + q2.y + q2.w + q3.y + q3.w;
            if (tid == 0) {
                tout[rbase + 2 * k + 0] = tvA;
                tout[rbase + 2 * k + 1] = tvB;
                ttacc += tvA * tvA + tvB * tvB;
            }
            #pragma unroll
            for (int j = 0; j < 16; ++j) sacc[j] += tvA * f0[j] + tvB * f1[j];
            c0 = n0; c1 = n1;                 // register renames
        }
        if (tid == 0) atomicAdd(ttout, ttacc);
    }

    float4* sp = (float4*)(spart + (size_t)blockIdx.x * NN) + tid * 4;
    #pragma unroll
    for (int q = 0; q < 4; ++q) {
        float4 w;
        w.x = sacc[4*q+0]; w.y = sacc[4*q+1];
        w.z = sacc[4*q+2]; w.w = sacc[4*q+3];
        sp[q] = w;
    }
}

// --- combine spart column-wise -> s ; apply CG update ----------------------
// 256 blocks x 512 thr; block owns 32 CONSECUTIVE cols (= one 128 B line;
// spart rows are 128 B aligned) -> all 256 CUs active, zero line waste.
// Thread (pg=tid>>5, colq=tid&31): sums nb/16 partials for col=blk*32+colq.
// mode 0: r = s, RS += s^2
// mode 1: alpha=RS/TT; v += alpha pn; qh += alpha t; r -= alpha s; RS' += r^2
__global__ __launch_bounds__(512) void reduce_update(
        const float* __restrict__ spart, int nb,
        const float* __restrict__ t,
        const float* __restrict__ pn,
        float* __restrict__ r,
        float* __restrict__ v,
        float* __restrict__ qh,
        const float* __restrict__ sc,
        int anum, int aden,
        float* __restrict__ rsout,
        int mode) {
    const int tid  = threadIdx.x;
    const int colq = tid & 31;            // 0..31: column within block
    const int pg   = tid >> 5;            // 0..15: partial-group
    const int col  = blockIdx.x * 32 + colq;
    const int per  = nb >> 4;             // partials per group (nb=512 -> 32)
    float s = 0.f;
    #pragma unroll 8
    for (int i = 0; i < per; ++i)
        s += spart[(size_t)(pg * per + i) * NN + col];
    __shared__ float sred[16][33];
    sred[pg][colq] = s;
    __syncthreads();
    float rn2 = 0.f;
    if (tid < 32) {
        float ssum = 0.f;
        #pragma unroll
        for (int g = 0; g < 16; ++g) ssum += sred[g][tid];
        const int c = blockIdx.x * 32 + tid;
        float rn;
        if (mode == 0) {
            rn = ssum;
        } else {
            const float alpha = sc[anum] / (sc[aden] + EPSF);
            v[c]  += alpha * pn[c];
            qh[c] += alpha * t[c];
            rn = r[c] - alpha * ssum;
        }
        r[c] = rn;
        rn2 = rn * rn;
    }
    if (tid < 64) {
        rn2 = wave_red(rn2);
        if (tid == 0) atomicAdd(rsout, rn2);
    }
}

// --- prep: zero v, qh and scalar slots ------------------------------------
__global__ __launch_bounds__(256) void prep(float* v, float* qh, float* sc) {
    const int i = blockIdx.x * 256 + threadIdx.x;
    v[i] = 0.f; qh[i] = 0.f;
    if (i < 128) sc[i] = 0.f;
}

// --- time-domain metrics + difference signals + v output ------------------
__global__ __launch_bounds__(256) void metrics1(const float* __restrict__ qh,
                                                const float* __restrict__ v,
                                                const float* __restrict__ x,
                                                const float* __restrict__ vt,
                                                const float* __restrict__ qt,
                                                float* __restrict__ dv,
                                                float* __restrict__ dq,
                                                float* msc,
                                                float* __restrict__ out) {
    const int i = blockIdx.x * 256 + threadIdx.x;
    const float qhv = qh[i], vv = v[i];
    const float xv = x[i], vtv = vt[i], qtv = qt[i];
    const float dqi = qhv - qtv, dvi = vv - vtv;
    dq[i] = dqi; dv[i] = dvi;
    out[i] = vv;
    const float sg = (i & 1) ? -1.f : 1.f;
    const float rx = qhv - xv;
    wred_atomic(rx * rx,    &msc[3]);
    wred_atomic(fabsf(dqi), &msc[4]);
    wred_atomic(dqi * dqi,  &msc[5]);
    wred_atomic(qtv * qtv,  &msc[6]);
    wred_atomic(fabsf(dvi), &msc[7]);
    wred_atomic(dvi * dvi,  &msc[8]);
    wred_atomic(vtv * vtv,  &msc[9]);
    wred_atomic(dqi,        &msc[10]);
    wred_atomic(sg * dqi,   &msc[11]);
    wred_atomic(qtv,        &msc[12]);
    wred_atomic(sg * qtv,   &msc[13]);
    wred_atomic(dvi,        &msc[14]);
    wred_atomic(sg * dvi,   &msc[15]);
    wred_atomic(vtv,        &msc[16]);
    wred_atomic(sg * vtv,   &msc[17]);
}

// --- direct rDFT magnitudes: one wave per bin k (0..4096) ------------------
__global__ __launch_bounds__(256) void dftmag(const float* __restrict__ dv,
                                              const float* __restrict__ dq,
                                              float* msc) {
    const int wave = threadIdx.x >> 6;
    const int lane = threadIdx.x & 63;
    const int k = blockIdx.x * 4 + wave;
    const float* sig = blockIdx.y ? dq : dv;
    float re = 0.f, im = 0.f;
    if (k <= 4096) {
        const float C = 2.0f * 3.14159265358979323846f / 8192.0f;
        int phase = (k * lane) & 8191;
        const int step = (k << 6) & 8191;
        for (int j = 0; j < 128; ++j) {
            const float s = sig[j * 64 + lane];
            float sn, cs;
            sincosf(C * (float)phase, &sn, &cs);
            re += s * cs; im += s * sn;
            phase = (phase + step) & 8191;
        }
    }
    re = wave_red(re); im = wave_red(im);
    __shared__ float mg[4];
    if (lane == 0) mg[wave] = (k <= 4096) ? sqrtf(re * re + im * im) : 0.f;
    __syncthreads();
    if (threadIdx.x == 0)
        atomicAdd(&msc[18 + blockIdx.y], mg[0] + mg[1] + mg[2] + mg[3]);
}

// --- finalize 11 scalar outputs -------------------------------------------
__global__ void finalize(const float* __restrict__ msc,
                         float* __restrict__ out) {
    if (threadIdx.x == 0 && blockIdx.x == 0) {
        const float Nf = 8192.0f;
        const float Sdq = 0.5f * (Nf * msc[5] + msc[10]*msc[10] + msc[11]*msc[11]);
        const float Sqt = 0.5f * (Nf * msc[6] + msc[12]*msc[12] + msc[13]*msc[13]);
        const float Sdv = 0.5f * (Nf * msc[8] + msc[14]*msc[14] + msc[15]*msc[15]);
        const float Svt = 0.5f * (Nf * msc[9] + msc[16]*msc[16] + msc[17]*msc[17]);
        out[8192 + 0]  = sqrtf(msc[3]);
        out[8192 + 1]  = msc[4] / Nf;
        out[8192 + 2]  = msc[5] / (msc[6] + EPSF);
        out[8192 + 3]  = msc[7] / Nf;
        out[8192 + 4]  = msc[8] / (msc[9] + EPSF);
        out[8192 + 5]  = msc[5] / Nf;
        out[8192 + 6]  = msc[8] / Nf;
        out[8192 + 7]  = msc[19] / 4097.0f;
        out[8192 + 8]  = Sdq / (Sqt + EPSF);
        out[8192 + 9]  = msc[18] / 4097.0f;
        out[8192 + 10] = Sdv / (Svt + EPSF);
    }
}

// ---------------------------------------------------------------------------
extern "C" void kernel_launch(void* const* d_in, const int* in_sizes, int n_in,
                              void* d_out, int out_size, void* d_ws, size_t ws_size,
                              hipStream_t stream) {
    const float* x  = (const float*)d_in[1];
    const float* H  = (const float*)d_in[2];
    const float* vt = (const float*)d_in[3];
    const float* qt = (const float*)d_in[4];

    const size_t HH_BYTES  = (size_t)NN * NN * 2;   // 134,217,728 (fp16 H)
    const size_t VEC_BYTES = 80000ull * 4;

    int nb = 512;                                    // row-blocks in fused pass
    const bool fp16ok =
        ws_size >= HH_BYTES + (size_t)512 * NN * 4 + VEC_BYTES;

    ushort_t* Hh = (ushort_t*)d_ws;
    float* spart;
    float* vecs;
    if (fp16ok) {
        spart = (float*)((char*)d_ws + HH_BYTES);
        vecs  = spart + (size_t)512 * NN;
    } else {
        // fp32-direct fallback: only spart + vectors in ws
        while (nb > 64 && ws_size < (size_t)nb * NN * 4 + VEC_BYTES) nb >>= 1;
        spart = (float*)d_ws;
        vecs  = spart + (size_t)nb * NN;
    }
    const int rpb = NN / nb;

    float* v   = vecs;
    float* r   = vecs + 8192;
    float* pA  = vecs + 16384;
    float* pB  = vecs + 24576;
    float* t   = vecs + 32768;
    float* qh  = vecs + 40960;
    float* dv  = vecs + 49152;
    float* dq  = vecs + 57344;
    float* sc  = vecs + 65536;
    float* msc = sc + 80;
    float* out = (float*)d_out;
    float* pbuf[2] = { pA, pB };

    prep<<<32, 256, 0, stream>>>(v, qh, sc);

    // init: b = H^T x  ->  r = b, RS[0] = b.b   (+ fp16 convert when fp16ok)
    if (fp16ok)
        fused_pass<0, 1><<<nb, 512, 0, stream>>>(H, Hh, r, r, x, sc,
                                                 0, 0, 1, 0, rpb,
                                                 t, &sc[79], pA, spart);
    else
        fused_pass<0, 0><<<nb, 512, 0, stream>>>(H, nullptr, r, r, x, sc,
                                                 0, 0, 1, 0, rpb,
                                                 t, &sc[79], pA, spart);
    reduce_update<<<256, 512, 0, stream>>>(spart, nb, t, pA, r, v, qh, sc,
                                           0, 0, &sc[0], 0);

    for (int it = 0; it < NITER; ++it) {
        const float* pread = (it == 0) ? r : pbuf[(it - 1) & 1];
        float* pwrite = pbuf[it & 1];
        if (fp16ok)
            fused_pass<1, 0><<<nb, 512, 0, stream>>>(Hh, nullptr, r, pread, x,
                                                     sc, it, it - 1,
                                                     (it == 0) ? 1 : 0, 1, rpb,
                                                     t, &sc[40 + it],
                                                     pwrite, spart);
        else
            fused_pass<0, 0><<<nb, 512, 0, stream>>>(H, nullptr, r, pread, x,
                                                     sc, it, it - 1,
                                                     (it == 0) ? 1 : 0, 1, rpb,
                                                     t, &sc[40 + it],
                                                     pwrite, spart);
        reduce_update<<<256, 512, 0, stream>>>(spart, nb, t, pwrite, r, v, qh,
                                               sc, it, 40 + it, &sc[it + 1], 1);
    }

    metrics1<<<32, 256, 0, stream>>>(qh, v, x, vt, qt, dv, dq, msc, out);
    dim3 g(1025, 2);
    dftmag<<<g, 256, 0, stream>>>(dv, dq, msc);
    finalize<<<1, 64, 0, stream>>>(sc + 80, out);
}